// Round 5
// baseline (77.331 us; speedup 1.0000x reference)
//
#include <hip/hip_runtime.h>
#include <stdint.h>

#define NB 4096     // B
#define ND 256      // D

typedef __attribute__((ext_vector_type(8))) short short8;   // 8 bf16 = 4 VGPR
typedef __attribute__((ext_vector_type(4))) float f32x4;

// fp32 -> bf16 RNE
__device__ __forceinline__ unsigned short f2bf(float f) {
    unsigned int u = __float_as_uint(f);
    u += 0x7FFFu + ((u >> 16) & 1u);
    return (unsigned short)(u >> 16);
}

// ---------------- prep: normalize rows (cos via plain dot), bf16 cast ----------------
__global__ void __launch_bounds__(256) prep_kernel(
    const float* __restrict__ A, const float* __restrict__ Bf,
    unsigned short* __restrict__ Abf, unsigned short* __restrict__ Bbf,
    float* __restrict__ lossws)
{
    if (blockIdx.x == 0 && threadIdx.x < 64) lossws[threadIdx.x << 5] = 0.0f;
    int gw   = (blockIdx.x * 256 + threadIdx.x) >> 6;   // global wave id 0..8191
    int lane = threadIdx.x & 63;
    const float* src; unsigned short* dst; int row;
    if (gw < NB) { src = A;  dst = Abf; row = gw; }
    else         { src = Bf; dst = Bbf; row = gw - NB; }

    float4 v = reinterpret_cast<const float4*>(src + (size_t)row * ND)[lane];
    float ss = v.x * v.x + v.y * v.y + v.z * v.z + v.w * v.w;
    #pragma unroll
    for (int off = 1; off < 64; off <<= 1) ss += __shfl_xor(ss, off);
    float rn = 1.0f / sqrtf(fmaxf(ss, 1e-30f));   // norms ~16, eps never binds

    ushort4 u;
    u.x = f2bf(v.x * rn); u.y = f2bf(v.y * rn);
    u.z = f2bf(v.z * rn); u.w = f2bf(v.w * rn);
    reinterpret_cast<ushort4*>(dst + (size_t)row * ND)[lane] = u;
}

// ---------------- banded GEMM, direct L2->VGPR operands, fused epilogue ----------------
// Block (bk,bs) owns out rows s in [s0,s0+64), cols k in [k0,k0+128).
// Wave w: k-strip [k0+32w, +32) (2 A-frags), j-window [k0+s0+32w, +96) (6 B-frags),
// 10 MFMA per K=32 step. NO LDS and NO barriers in the main loop: operand
// fragments are naturally-coalesced global loads (16 rows x 64B lines), A+B are
// L2-resident (4 MB total). LDS only for the diagonal epilogue bounce.
__global__ void __launch_bounds__(256, 4) gemm_kernel(
    const unsigned short* __restrict__ Abf, const unsigned short* __restrict__ Bbf,
    const float* __restrict__ labels, float* __restrict__ out,
    float* __restrict__ lossws)
{
    __shared__ __align__(16) float dw[64 * 128];   // 32 KB diagonal bounce
    __shared__ float lpart[4];

    const int tid = threadIdx.x;
    const int w = tid >> 6, lane = tid & 63;
    const int lane15 = lane & 15, lhi = lane >> 4;
    const int bk = blockIdx.x & 31, bs = blockIdx.x >> 5;
    const int k0 = bk << 7, s0 = bs << 6;
    const int kw = k0 + (w << 5);

    // per-lane fragment base pointers; per-step offset is a folded immediate
    const short8* aptr[2];
    const short8* bptr[6];
    #pragma unroll
    for (int m = 0; m < 2; ++m)
        aptr[m] = reinterpret_cast<const short8*>(
            Abf + (size_t)(kw + (m << 4) + lane15) * ND) + lhi;
    #pragma unroll
    for (int jf = 0; jf < 6; ++jf) {
        int row = (kw + s0 + (jf << 4) + lane15) & (NB - 1);
        bptr[jf] = reinterpret_cast<const short8*>(
            Bbf + (size_t)row * ND) + lhi;
    }

    f32x4 acc[2][5];
    #pragma unroll
    for (int m = 0; m < 2; ++m)
        #pragma unroll
        for (int r = 0; r < 5; ++r) acc[m][r] = (f32x4)0.0f;

    #pragma unroll
    for (int ks = 0; ks < 8; ++ks) {          // K = 256 in 8 steps of 32
        short8 a[2], b[6];
        #pragma unroll
        for (int m = 0; m < 2; ++m) a[m] = aptr[m][ks << 2];
        #pragma unroll
        for (int jf = 0; jf < 6; ++jf) b[jf] = bptr[jf][ks << 2];
        #pragma unroll
        for (int m = 0; m < 2; ++m)
            #pragma unroll
            for (int r = 0; r < 5; ++r)
                acc[m][r] = __builtin_amdgcn_mfma_f32_16x16x32_bf16(
                    a[m], b[m + r], acc[m][r], 0, 0, 0);
    }

    // ---- scatter: (t, kap) -> dw[t][kap ^ (t&31)]  (~2-way banks) ----
    // t = s-local = 16r + lane15 - 4lhi - e in [0,64); kap = block-local k col
    #pragma unroll
    for (int m = 0; m < 2; ++m)
        #pragma unroll
        for (int r = 0; r < 5; ++r)
            #pragma unroll
            for (int e = 0; e < 4; ++e) {
                int t = (r << 4) + lane15 - (lhi << 2) - e;
                if ((unsigned)t < 64u) {
                    int kap = (w << 5) + (m << 4) + (lhi << 2) + e;
                    dw[(t << 7) + (kap ^ (t & 31))] = acc[m][r][e];
                }
            }
    __syncthreads();

    // ---- gather rows (strided ownership t = w + 4*lane15), store + loss ----
    const int t = w + (lane15 << 2);
    const int s = s0 + t;
    const int x3 = w & 3;                      // wave-uniform within-quad perm
    const float* rowp = dw + (t << 7);
    float lacc = 0.0f;

    #pragma unroll
    for (int i = 0; i < 8; ++i) {
        int qlog  = lhi + (i << 2);            // logical quad 0..31
        int physq = qlog ^ (lane15 & 7);       // 8 distinct bank-quads per instr
        f32x4 d = *reinterpret_cast<const f32x4*>(rowp + (physq << 2));
        f32x4 v;
        if      (x3 == 0) { v = d; }
        else if (x3 == 1) { v[0] = d[1]; v[1] = d[0]; v[2] = d[3]; v[3] = d[2]; }
        else if (x3 == 2) { v[0] = d[2]; v[1] = d[3]; v[2] = d[0]; v[3] = d[1]; }
        else              { v[0] = d[3]; v[1] = d[2]; v[2] = d[1]; v[3] = d[0]; }

        f32x4 x, y;
        #pragma unroll
        for (int e = 0; e < 4; ++e) {
            x[e] = fmaf(v[e],  0.5f, 0.5f);    // logit
            y[e] = fmaf(v[e], -0.5f, 0.5f);    // 1 - logit (exact)
        }
        *reinterpret_cast<f32x4*>(out + (size_t)s * NB + k0 + (qlog << 2)) = x;

        float l1p0 = fmaxf(__logf(y[0]), -100.0f);
        float l1p1 = fmaxf(__logf(y[1]), -100.0f);
        float l1p2 = fmaxf(__logf(y[2]), -100.0f);
        float l1p3 = fmaxf(__logf(y[3]), -100.0f);
        if (s == 0) {   // weight-1 labeled row
            float l1pv[4] = {l1p0, l1p1, l1p2, l1p3};
            #pragma unroll
            for (int e = 0; e < 4; ++e) {
                float lab = labels[k0 + (qlog << 2) + e];
                float lp  = fmaxf(__logf(x[e]), -100.0f);
                lacc += lab * lp + (1.0f - lab) * l1pv[e];
            }
        } else {
            lacc += 0.5f * (l1p0 + l1p1 + l1p2 + l1p3);   // NEG_WEIGHT
        }
    }

    #pragma unroll
    for (int off = 32; off > 0; off >>= 1) lacc += __shfl_down(lacc, off);
    if (lane == 0) lpart[w] = lacc;
    __syncthreads();
    if (tid == 0) {
        float tot = lpart[0] + lpart[1] + lpart[2] + lpart[3];
        atomicAdd(lossws + ((blockIdx.x & 63) << 5), -tot);
    }
}

__global__ void finalize_kernel(const float* __restrict__ lossws, float* __restrict__ out) {
    float s = 0.0f;
    for (int i = 0; i < 64; ++i) s += lossws[i << 5];
    out[(size_t)NB * NB] = s;
}

extern "C" void kernel_launch(void* const* d_in, const int* in_sizes, int n_in,
                              void* d_out, int out_size, void* d_ws, size_t ws_size,
                              hipStream_t stream) {
    (void)in_sizes; (void)n_in; (void)out_size; (void)ws_size;
    const float* A      = (const float*)d_in[0];
    const float* Bf     = (const float*)d_in[1];
    const float* labels = (const float*)d_in[2];
    float* out = (float*)d_out;

    char* ws = (char*)d_ws;
    unsigned short* Abf = (unsigned short*)ws;                                  // 2 MB
    unsigned short* Bbf = (unsigned short*)(ws + (size_t)2 * 1024 * 1024);      // 2 MB
    float* lossws = (float*)(ws + (size_t)4 * 1024 * 1024);                     // 8 KB (64 cells x 128B)

    hipLaunchKernelGGL(prep_kernel, dim3(2048), dim3(256), 0, stream,
                       A, Bf, Abf, Bbf, lossws);
    hipLaunchKernelGGL(gemm_kernel, dim3(2048), dim3(256), 0, stream,
                       Abf, Bbf, labels, out, lossws);
    hipLaunchKernelGGL(finalize_kernel, dim3(1), dim3(1), 0, stream, lossws, out);
}

// Round 6
// 47.328 us; speedup vs baseline: 1.6340x; 1.6340x over previous
//
#include <hip/hip_runtime.h>
#include <stdint.h>

#define NB 4096     // B
#define ND 256      // D

typedef __attribute__((ext_vector_type(8))) short short8;   // 8 bf16 = 4 VGPR
typedef __attribute__((ext_vector_type(4))) float f32x4;

// fp32 -> bf16 RNE
__device__ __forceinline__ unsigned short f2bf(float f) {
    unsigned int u = __float_as_uint(f);
    u += 0x7FFFu + ((u >> 16) & 1u);
    return (unsigned short)(u >> 16);
}

// async global->LDS, 16B per lane. lds dest = wave-uniform base + lane*16.
__device__ __forceinline__ void gload16(const void* g, void* lds_uniform) {
    __builtin_amdgcn_global_load_lds(
        (const __attribute__((address_space(1))) void*)(uintptr_t)g,
        (__attribute__((address_space(3))) void*)(unsigned int)(uintptr_t)lds_uniform,
        16, 0, 0);
}

// ---------------- prep: normalize rows (cos via plain dot), bf16 cast ----------------
__global__ void __launch_bounds__(256) prep_kernel(
    const float* __restrict__ A, const float* __restrict__ Bf,
    unsigned short* __restrict__ Abf, unsigned short* __restrict__ Bbf,
    float* __restrict__ lossws)
{
    if (blockIdx.x == 0 && threadIdx.x < 64) lossws[threadIdx.x << 5] = 0.0f;
    int gw   = (blockIdx.x * 256 + threadIdx.x) >> 6;   // global wave id 0..8191
    int lane = threadIdx.x & 63;
    const float* src; unsigned short* dst; int row;
    if (gw < NB) { src = A;  dst = Abf; row = gw; }
    else         { src = Bf; dst = Bbf; row = gw - NB; }

    float4 v = reinterpret_cast<const float4*>(src + (size_t)row * ND)[lane];
    float ss = v.x * v.x + v.y * v.y + v.z * v.z + v.w * v.w;
    #pragma unroll
    for (int off = 1; off < 64; off <<= 1) ss += __shfl_xor(ss, off);
    float rn = 1.0f / sqrtf(fmaxf(ss, 1e-30f));   // norms ~16, eps never binds

    ushort4 u;
    u.x = f2bf(v.x * rn); u.y = f2bf(v.y * rn);
    u.z = f2bf(v.z * rn); u.w = f2bf(v.w * rn);
    reinterpret_cast<ushort4*>(dst + (size_t)row * ND)[lane] = u;
}

// ---------------- fused banded GEMM + row-owned epilogue + BCE loss ----------------
// Block (bk,bs) OWNS out rows s in [s0,s0+64), cols k in [k0,k0+128).
// Band: B-rows j in [k0+s0, k0+s0+192). 4 waves; wave w owns k-strip
// [32w,32w+32): 2 A-frags + 6 B-frags -> 10 MFMA per K=32 step (1.25x overcompute).
// BK=32 double-buffered global_load_lds staging (2 x 20KB), issue-early schedule.
__global__ void __launch_bounds__(256, 4) gemm_kernel(
    const unsigned short* __restrict__ Abf, const unsigned short* __restrict__ Bbf,
    const float* __restrict__ labels, float* __restrict__ out,
    float* __restrict__ lossws)
{
    // buf0 [0,20480): A 8K | B 12K ; buf1 [20480,40960)
    // epilogue: dw [0,32768) (64 x 128 f32); lpart [32768,32784)
    __shared__ __align__(16) char smem[40960];

    const int tid = threadIdx.x;
    const int w = tid >> 6, lane = tid & 63;
    const int lane15 = lane & 15, lhi = lane >> 4;
    const int bk = blockIdx.x & 31, bs = blockIdx.x >> 5;
    const int k0 = bk << 7, s0 = bs << 6;
    const int j0 = (k0 + s0) & (NB - 1);

    f32x4 acc[2][5];
    #pragma unroll
    for (int m = 0; m < 2; ++m)
        #pragma unroll
        for (int r = 0; r < 5; ++r) acc[m][r] = (f32x4)0.0f;

    // stage K-chunk kt (BK=32, 64B rows of 4x16B chunks) into buffer buf.
    // physical chunk pc at row holds logical chunk pc ^ f(row), f=(row^(row>>2))&3
    auto stage = [&](int kt, char* buf) {
        #pragma unroll
        for (int i = 0; i < 2; ++i) {         // A: 128 rows -> 512 slots
            int slot0 = (i << 8) + (w << 6);  // wave-uniform
            int slot  = slot0 + lane;
            int row   = slot >> 2;
            int sch   = (slot ^ (slot >> 2) ^ (slot >> 4)) & 3;
            gload16(Abf + (size_t)(k0 + row) * ND + (kt << 5) + (sch << 3), buf + slot0 * 16);
        }
        #pragma unroll
        for (int i = 0; i < 3; ++i) {         // B: 192 rows -> 768 slots
            int slot0 = (i << 8) + (w << 6);
            int slot  = slot0 + lane;
            int row   = slot >> 2;
            int srow  = (j0 + row) & (NB - 1);
            int sch   = (slot ^ (slot >> 2) ^ (slot >> 4)) & 3;
            gload16(Bbf + (size_t)srow * ND + (kt << 5) + (sch << 3), buf + 8192 + slot0 * 16);
        }
    };

    stage(0, smem);
    __syncthreads();   // vmcnt(0): buf0 ready

    for (int kt = 0; kt < 8; ++kt) {          // K = 256 in 8 chunks of BK=32
        char* buf = smem + ((kt & 1) ? 20480 : 0);
        if (kt < 7) stage(kt + 1, smem + ((kt & 1) ? 0 : 20480));  // prefetch overlaps compute
        const int f = (lane15 ^ (lane15 >> 2)) & 3;   // = f(row) for all rows read below
        short8 a[2], b[6];
        #pragma unroll
        for (int m = 0; m < 2; ++m) {
            int row = (w << 5) + (m << 4) + lane15;
            a[m] = *reinterpret_cast<const short8*>(buf + row * 64 + ((lhi ^ f) << 4));
        }
        #pragma unroll
        for (int jf = 0; jf < 6; ++jf) {
            int row = (w << 5) + (jf << 4) + lane15;
            b[jf] = *reinterpret_cast<const short8*>(buf + 8192 + row * 64 + ((lhi ^ f) << 4));
        }
        #pragma unroll
        for (int m = 0; m < 2; ++m)
            #pragma unroll
            for (int r = 0; r < 5; ++r)
                acc[m][r] = __builtin_amdgcn_mfma_f32_16x16x32_bf16(
                    a[m], b[m + r], acc[m][r], 0, 0, 0);
        __syncthreads();   // reads done; prefetched buffer landed
    }

    // ---- scatter: (t, kap) -> dw[t][kap ^ (t&31)]  (measured ~free banks) ----
    // t = s-local = 16r + lane15 - 4lhi - e in [0,64); kap = block-local k col
    float* dw    = reinterpret_cast<float*>(smem);          // 64 x 128 f32
    float* lpart = reinterpret_cast<float*>(smem + 32768);  // 4 f32
    #pragma unroll
    for (int m = 0; m < 2; ++m)
        #pragma unroll
        for (int r = 0; r < 5; ++r)
            #pragma unroll
            for (int e = 0; e < 4; ++e) {
                int t = (r << 4) + lane15 - (lhi << 2) - e;
                if ((unsigned)t < 64u) {
                    int kap = (w << 5) + (m << 4) + (lhi << 2) + e;
                    dw[(t << 7) + (kap ^ (t & 31))] = acc[m][r][e];
                }
            }
    __syncthreads();

    // ---- gather rows (strided ownership t = w + 4*lane15), store + loss ----
    const int t = w + (lane15 << 2);
    const int s = s0 + t;
    const int x3 = w & 3;                      // wave-uniform within-quad perm
    const float* rowp = dw + (t << 7);
    float lacc = 0.0f;

    #pragma unroll
    for (int i = 0; i < 8; ++i) {
        int qlog  = lhi + (i << 2);            // logical quad 0..31
        int physq = qlog ^ (lane15 & 7);       // 8 distinct bank-quads per instr
        f32x4 d = *reinterpret_cast<const f32x4*>(rowp + (physq << 2));
        f32x4 v;
        if      (x3 == 0) { v = d; }
        else if (x3 == 1) { v[0] = d[1]; v[1] = d[0]; v[2] = d[3]; v[3] = d[2]; }
        else if (x3 == 2) { v[0] = d[2]; v[1] = d[3]; v[2] = d[0]; v[3] = d[1]; }
        else              { v[0] = d[3]; v[1] = d[2]; v[2] = d[1]; v[3] = d[0]; }

        f32x4 x, y;
        #pragma unroll
        for (int e = 0; e < 4; ++e) {
            x[e] = fmaf(v[e],  0.5f, 0.5f);    // logit
            y[e] = fmaf(v[e], -0.5f, 0.5f);    // 1 - logit (exact)
        }
        *reinterpret_cast<f32x4*>(out + (size_t)s * NB + k0 + (qlog << 2)) = x;

        float l1p0 = fmaxf(__logf(y[0]), -100.0f);
        float l1p1 = fmaxf(__logf(y[1]), -100.0f);
        float l1p2 = fmaxf(__logf(y[2]), -100.0f);
        float l1p3 = fmaxf(__logf(y[3]), -100.0f);
        if (s == 0) {   // weight-1 labeled row
            float l1pv[4] = {l1p0, l1p1, l1p2, l1p3};
            #pragma unroll
            for (int e = 0; e < 4; ++e) {
                float lab = labels[k0 + (qlog << 2) + e];
                float lp  = fmaxf(__logf(x[e]), -100.0f);
                lacc += lab * lp + (1.0f - lab) * l1pv[e];
            }
        } else {
            lacc += 0.5f * (l1p0 + l1p1 + l1p2 + l1p3);   // NEG_WEIGHT
        }
    }

    #pragma unroll
    for (int off = 32; off > 0; off >>= 1) lacc += __shfl_down(lacc, off);
    if (lane == 0) lpart[w] = lacc;
    __syncthreads();
    if (tid == 0) {
        float tot = lpart[0] + lpart[1] + lpart[2] + lpart[3];
        atomicAdd(lossws + ((blockIdx.x & 63) << 5), -tot);
    }
}

__global__ void finalize_kernel(const float* __restrict__ lossws, float* __restrict__ out) {
    float s = 0.0f;
    for (int i = 0; i < 64; ++i) s += lossws[i << 5];
    out[(size_t)NB * NB] = s;
}

extern "C" void kernel_launch(void* const* d_in, const int* in_sizes, int n_in,
                              void* d_out, int out_size, void* d_ws, size_t ws_size,
                              hipStream_t stream) {
    (void)in_sizes; (void)n_in; (void)out_size; (void)ws_size;
    const float* A      = (const float*)d_in[0];
    const float* Bf     = (const float*)d_in[1];
    const float* labels = (const float*)d_in[2];
    float* out = (float*)d_out;

    char* ws = (char*)d_ws;
    unsigned short* Abf = (unsigned short*)ws;                                  // 2 MB
    unsigned short* Bbf = (unsigned short*)(ws + (size_t)2 * 1024 * 1024);      // 2 MB
    float* lossws = (float*)(ws + (size_t)4 * 1024 * 1024);                     // 8 KB (64 cells x 128B)

    hipLaunchKernelGGL(prep_kernel, dim3(2048), dim3(256), 0, stream,
                       A, Bf, Abf, Bbf, lossws);
    hipLaunchKernelGGL(gemm_kernel, dim3(2048), dim3(256), 0, stream,
                       Abf, Bbf, labels, out, lossws);
    hipLaunchKernelGGL(finalize_kernel, dim3(1), dim3(1), 0, stream, lossws, out);
}